// Round 16
// baseline (315.587 us; speedup 1.0000x reference)
//
#include <hip/hip_runtime.h>
#include <math.h>

#define BB 8
#define LL 4096
#define DD 64
#define KK 24
#define KT 27       // 24 spectral filters + 3 AR-U taps
#define NN 8192
#define LOGN 13
#define NP 4128     // padded half-spectrum rows per batch (129 tiles * 32)
#define NCH 256     // chunks per batch
#define CH 16       // timesteps per chunk
#define PAD 80      // LDS row pitch in u16 (40 dwords -> conflict-free b128 reads)
#define NKMAX 14

typedef unsigned int uint;
typedef unsigned short u16;
typedef __attribute__((ext_vector_type(8))) short bf16x8;
typedef __attribute__((ext_vector_type(4))) float f32x4;

__device__ __forceinline__ float bfl(uint u) {
    union { uint u; float f; } v; v.u = u << 16; return v.f;
}
__device__ __forceinline__ float bfh(uint u) {
    union { uint u; float f; } v; v.u = u & 0xFFFF0000u; return v.f;
}
__device__ __forceinline__ uint pk(float x) {
    union { float f; uint u; } v; v.f = x;
    return (v.u + 0x7FFFu + ((v.u >> 16) & 1u)) >> 16;
}
__device__ __forceinline__ float2 unpk2(uint u) {
    return make_float2(bfl(u), bfh(u));
}
__device__ __forceinline__ int br13(int v) { return (int)(__brev((uint)v) >> 19); }

// ---------------- FFT primitives, twiddles from a global L2-resident table ----------------
__global__ __launch_bounds__(512) void k_twiddle(float2* __restrict__ twc) {
    int i = blockIdx.x * 512 + threadIdx.x;
    if (i >= 8192) return;
    if (i == 0) { twc[0] = make_float2(1.f, 0.f); return; }
    int lh = 31 - __builtin_clz((uint)i);
    int j = i - (1 << lh);
    float ang = -6.28318530717958647692f * (float)j / (float)(2 << lh);
    float sn, cs;
    __sincosf(ang, &sn, &cs);
    twc[i] = make_float2(cs, sn);
}

template<int NT>
__device__ __forceinline__ void fft_dif(float2* a, const float2* __restrict__ twc) {
    const int tid = threadIdx.x;
    for (int lh = LOGN - 1; lh >= 0; --lh) {
        const int half = 1 << lh;
#pragma unroll
        for (int bb = 0; bb < NN / 2 / NT; ++bb) {
            int t = tid + bb * NT;
            int j = t & (half - 1);
            int i0 = ((t >> lh) << (lh + 1)) + j;
            float2 u = a[i0], v = a[i0 + half];
            float2 w = twc[half + j];
            float cs = w.x, sn = w.y;
            float dx = u.x - v.x, dy = u.y - v.y;
            a[i0] = make_float2(u.x + v.x, u.y + v.y);
            a[i0 + half] = make_float2(dx * cs - dy * sn, dx * sn + dy * cs);
        }
        __syncthreads();
    }
}

template<int NT>
__device__ __forceinline__ void fft_dit(float2* a, const float2* __restrict__ twc) {
    const int tid = threadIdx.x;
    for (int lh = 0; lh < LOGN; ++lh) {
        const int half = 1 << lh;
#pragma unroll
        for (int bb = 0; bb < NN / 2 / NT; ++bb) {
            int t = tid + bb * NT;
            int j = t & (half - 1);
            int i0 = ((t >> lh) << (lh + 1)) + j;
            float2 u = a[i0], v = a[i0 + half];
            float2 w = twc[half + j];
            float cs = w.x, sn = -w.y;      // conjugate for inverse
            float wx = v.x * cs - v.y * sn;
            float wy = v.x * sn + v.y * cs;
            a[i0] = make_float2(u.x + wx, u.y + wy);
            a[i0 + half] = make_float2(u.x - wx, u.y - wy);
        }
        __syncthreads();
    }
}

// ---------------- kernels ----------------

// Pack 27 B-slabs, o-major bf16 c-pair: slabs 0..23 = m_phi[k], 24..26 = m_u[:,:,ku].
__global__ __launch_bounds__(256) void k_pack(const float* __restrict__ mphi,
                                              const float* __restrict__ mu,
                                              uint* __restrict__ mp2) {
    int idx = blockIdx.x * 256 + threadIdx.x;
    if (idx >= KT * 2048) return;
    int k = idx >> 11;
    int rem = idx & 2047;
    int o = rem >> 5, cp = rem & 31;
    int c = cp * 2;
    uint v;
    if (k < KK) {
        v = pk(mphi[(k * 64 + c) * 64 + o]) | (pk(mphi[(k * 64 + c + 1) * 64 + o]) << 16);
    } else {
        int ku = k - KK;
        v = pk(mu[(o * 64 + c) * 3 + ku]) | (pk(mu[(o * 64 + c + 1) * 3 + ku]) << 16);
    }
    mp2[idx] = v;
}

// V[f,k] = FFT(eig_vecs[:,k] * lambda_k^0.25 / N), bit-reversed bins, fp32
__global__ __launch_bounds__(256) void k_fft_filters(const float* __restrict__ eig_vals,
                                                     const float* __restrict__ eig_vecs,
                                                     const float2* __restrict__ twc,
                                                     float2* __restrict__ Vb) {
    __shared__ float2 a[NN];
    const int k = blockIdx.x, tid = threadIdx.x;
    const float alpha = powf(eig_vals[k], 0.25f) * (1.0f / (float)NN);
    for (int t = tid; t < LL; t += 256)
        a[t] = make_float2(eig_vecs[t * KK + k] * alpha, 0.f);
    for (int t = LL + tid; t < NN; t += 256)
        a[t] = make_float2(0.f, 0.f);
    __syncthreads();
    fft_dif<256>(a, twc);
    for (int r = tid; r < NN; r += 256)
        Vb[(size_t)r * KK + k] = a[r];
}

// Two real channels per complex FFT. Plane-major U out (planes sized NP).
__global__ __launch_bounds__(512) void k_fft_x2(const float* __restrict__ x,
                                                const float2* __restrict__ twc,
                                                uint* __restrict__ Uxp,
                                                uint* __restrict__ Uyp) {
    __shared__ float2 a[NN];
    const int b = blockIdx.x & 7, cp = blockIdx.x >> 3;
    const int tid = threadIdx.x;
    for (int l = tid; l < LL; l += 512)
        a[l] = *(const float2*)&x[((size_t)b * LL + l) * DD + 2 * cp];
    for (int l = LL + tid; l < NN; l += 512)
        a[l] = make_float2(0.f, 0.f);
    __syncthreads();
    fft_dif<512>(a, twc);
    const size_t plane = ((size_t)b * 32 + cp) * NP;
    for (int idx = tid; idx < 4097; idx += 512) {
        int r = (idx == 4096) ? 1 : 2 * idx;
        int fn = br13(r);
        int q = br13((8192 - fn) & 8191);
        float2 Z = a[r], W = a[q];
        float ucx = 0.5f * (Z.x + W.x), ucy = 0.5f * (Z.y - W.y);
        float upx = 0.5f * (Z.y + W.y), upy = 0.5f * (W.x - Z.x);
        Uxp[plane + idx] = pk(ucx) | (pk(upx) << 16);
        Uyp[plane + idx] = pk(ucy) | (pk(upy) << 16);
    }
    for (int idx = 4097 + tid; idx < NP; idx += 512) {
        Uxp[plane + idx] = 0;
        Uyp[plane + idx] = 0;
    }
}

// MFMA modulate v7: ALL nk B-slabs pre-staged in LDS (143 KB), one barrier,
// then a barrier-free LDS+MFMA inner loop. Two passes accumulate into bf16 S.
__global__ __launch_bounds__(256) void k_modulate7(const float2* __restrict__ Vb,
                                                   const uint* __restrict__ Uxp,
                                                   const uint* __restrict__ Uyp,
                                                   const uint* __restrict__ mp2,
                                                   uint* __restrict__ Sb2,
                                                   const int k0, const int nk,
                                                   const int accum) {
    __shared__ u16 mpT[NKMAX][64][PAD];    // 143.4 KB
    __shared__ u16 Uxs[32][72];            // 4.6 KB
    __shared__ u16 Uys[32][72];            // 4.6 KB
    __shared__ float2 Vt[32][NKMAX];       // 3.6 KB
    const int tid = threadIdx.x;
    const int pt = blockIdx.x;
    const int b  = blockIdx.y;
    const int p0 = pt * 32;

    // stage all B slabs for this pass: nk * 512 uint4
    for (int i = tid; i < nk * 512; i += 256) {
        int slab = i >> 9, e = i & 511;
        int o = e >> 3, seg = e & 7;
        uint4 m = ((const uint4*)&mp2[((size_t)(k0 + slab) * 64 + o) * 32])[seg];
        *(uint4*)&mpT[slab][o][seg * 8] = m;
    }
    // stage U tile
    for (int i = tid; i < 1024; i += 256) {
        int cp = i >> 5, row = i & 31;
        uint vx = Uxp[((size_t)b * 32 + cp) * NP + p0 + row];
        uint vy = Uyp[((size_t)b * 32 + cp) * NP + p0 + row];
        *(uint*)&Uxs[row][cp * 2] = vx;
        *(uint*)&Uys[row][cp * 2] = vy;
    }
    // stage V / AR phase scales for global k in [k0, k0+nk)
    for (int i = tid; i < 32 * nk; i += 256) {
        int pi = i / nk, kk = i - pi * nk;
        int kg = k0 + kk;
        int pidx = p0 + pi; if (pidx > 4096) pidx = 4096;
        int r = (pidx == 4096) ? 1 : 2 * pidx;
        if (kg < KK) {
            Vt[pi][kk] = Vb[(size_t)r * KK + kg];
        } else {
            int f = br13(r);
            const float invN = 1.f / 8192.f;
            float ph = -6.28318530717958647692f * (float)f * invN * (float)(kg - KK);
            float sn, cs;
            __sincosf(ph, &sn, &cs);
            Vt[pi][kk] = make_float2(cs * invN, sn * invN);
        }
    }
    __syncthreads();

    const int lane = tid & 63, w = tid >> 6;
    const int rt = w & 1, chalf = w >> 1;
    const int lrow = lane & 15, lk = lane >> 4;
    // A fragments hoisted out of the k-loop (k-independent)
    const u16* axp = &Uxs[rt * 16 + lrow][lk * 8];
    const u16* ayp = &Uys[rt * 16 + lrow][lk * 8];
    bf16x8 ax0 = *(const bf16x8*)(axp);
    bf16x8 ax1 = *(const bf16x8*)(axp + 32);
    bf16x8 ay0 = *(const bf16x8*)(ayp);
    bf16x8 ay1 = *(const bf16x8*)(ayp + 32);

    float Sx0[4] = {0.f, 0.f, 0.f, 0.f}, Sy0[4] = {0.f, 0.f, 0.f, 0.f};
    float Sx1[4] = {0.f, 0.f, 0.f, 0.f}, Sy1[4] = {0.f, 0.f, 0.f, 0.f};

    for (int kk = 0; kk < nk; ++kk) {
        const u16* bp0 = &mpT[kk][chalf * 32 + lrow][lk * 8];
        const u16* bp1 = &mpT[kk][chalf * 32 + 16 + lrow][lk * 8];
        bf16x8 b00 = *(const bf16x8*)(bp0);
        bf16x8 b01 = *(const bf16x8*)(bp0 + 32);
        bf16x8 b10 = *(const bf16x8*)(bp1);
        bf16x8 b11 = *(const bf16x8*)(bp1 + 32);
        float2 v0 = Vt[rt * 16 + lk * 4 + 0][kk];
        float2 v1 = Vt[rt * 16 + lk * 4 + 1][kk];
        float2 v2 = Vt[rt * 16 + lk * 4 + 2][kk];
        float2 v3 = Vt[rt * 16 + lk * 4 + 3][kk];
        f32x4 z = {0.f, 0.f, 0.f, 0.f};
        f32x4 Wx0 = __builtin_amdgcn_mfma_f32_16x16x32_bf16(ax0, b00, z, 0, 0, 0);
        Wx0 = __builtin_amdgcn_mfma_f32_16x16x32_bf16(ax1, b01, Wx0, 0, 0, 0);
        f32x4 Wy0 = __builtin_amdgcn_mfma_f32_16x16x32_bf16(ay0, b00, z, 0, 0, 0);
        Wy0 = __builtin_amdgcn_mfma_f32_16x16x32_bf16(ay1, b01, Wy0, 0, 0, 0);
        f32x4 Wx1 = __builtin_amdgcn_mfma_f32_16x16x32_bf16(ax0, b10, z, 0, 0, 0);
        Wx1 = __builtin_amdgcn_mfma_f32_16x16x32_bf16(ax1, b11, Wx1, 0, 0, 0);
        f32x4 Wy1 = __builtin_amdgcn_mfma_f32_16x16x32_bf16(ay0, b10, z, 0, 0, 0);
        Wy1 = __builtin_amdgcn_mfma_f32_16x16x32_bf16(ay1, b11, Wy1, 0, 0, 0);
        Sx0[0] += v0.x * Wx0[0] - v0.y * Wy0[0];  Sy0[0] += v0.x * Wy0[0] + v0.y * Wx0[0];
        Sx0[1] += v1.x * Wx0[1] - v1.y * Wy0[1];  Sy0[1] += v1.x * Wy0[1] + v1.y * Wx0[1];
        Sx0[2] += v2.x * Wx0[2] - v2.y * Wy0[2];  Sy0[2] += v2.x * Wy0[2] + v2.y * Wx0[2];
        Sx0[3] += v3.x * Wx0[3] - v3.y * Wy0[3];  Sy0[3] += v3.x * Wy0[3] + v3.y * Wx0[3];
        Sx1[0] += v0.x * Wx1[0] - v0.y * Wy1[0];  Sy1[0] += v0.x * Wy1[0] + v0.y * Wx1[0];
        Sx1[1] += v1.x * Wx1[1] - v1.y * Wy1[1];  Sy1[1] += v1.x * Wy1[1] + v1.y * Wx1[1];
        Sx1[2] += v2.x * Wx1[2] - v2.y * Wy1[2];  Sy1[2] += v2.x * Wy1[2] + v2.y * Wx1[2];
        Sx1[3] += v3.x * Wx1[3] - v3.y * Wy1[3];  Sy1[3] += v3.x * Wy1[3] + v3.y * Wx1[3];
    }
    const int rbase = rt * 16 + lk * 4;
    const int o0 = chalf * 32 + lrow;
    const size_t pl0 = ((size_t)b * 64 + o0) * NP + p0 + rbase;
    const size_t pl1 = ((size_t)b * 64 + o0 + 16) * NP + p0 + rbase;
    if (accum) {
#pragma unroll
        for (int j = 0; j < 4; ++j) {
            uint old0 = Sb2[pl0 + j], old1 = Sb2[pl1 + j];
            Sx0[j] += bfl(old0); Sy0[j] += bfh(old0);
            Sx1[j] += bfl(old1); Sy1[j] += bfh(old1);
        }
    }
#pragma unroll
    for (int j = 0; j < 4; ++j) {
        Sb2[pl0 + j] = pk(Sx0[j]) | (pk(Sy0[j]) << 16);
        Sb2[pl1 + j] = pk(Sx1[j]) | (pk(Sy1[j]) << 16);
    }
}

// Two output channels per inverse FFT; plane-major S in, plane-major deltas out.
__global__ __launch_bounds__(512) void k_ifft2(const uint* __restrict__ Sb2,
                                               const float2* __restrict__ twc,
                                               float* __restrict__ deltas) {
    __shared__ float2 a[NN];
    const int b = blockIdx.x & 7, op = blockIdx.x >> 3;
    const int tid = threadIdx.x;
    const uint* s0 = &Sb2[((size_t)b * 64 + op * 2) * NP];
    const uint* s1 = &Sb2[((size_t)b * 64 + op * 2 + 1) * NP];
    for (int idx = tid; idx < 4097; idx += 512) {
        int r = (idx == 4096) ? 1 : 2 * idx;
        float2 A = unpk2(s0[idx]), B = unpk2(s1[idx]);
        a[r] = make_float2(A.x - B.y, A.y + B.x);
        int fn = br13(r);
        int q = br13((8192 - fn) & 8191);
        if (q != r) a[q] = make_float2(A.x + B.y, B.x - A.y);
    }
    __syncthreads();
    fft_dit<512>(a, twc);
    float* d0 = &deltas[((size_t)b * 64 + op * 2) * LL];
    float* d1 = &deltas[((size_t)b * 64 + op * 2 + 1) * LL];
    for (int l = tid; l < LL; l += 512) {
        d0[l] = a[l].x;
        d1[l] = a[l].y;
    }
}

// First squaring with companion matrix built on the fly from m_y.
__global__ __launch_bounds__(256) void k_matsq1(const float* __restrict__ m_y,
                                                float* __restrict__ C) {
    int idx = blockIdx.x * 256 + threadIdx.x;
    int r = idx >> 7, c = idx & 127;
    if (r >= 64) { C[idx] = m_y[(r - 64) * 128 + c]; return; }
    float acc = (c < 64) ? m_y[r * 128 + 64 + c] : 0.f;
#pragma unroll
    for (int i = 0; i < 64; ++i) acc += m_y[r * 128 + i] * m_y[i * 128 + c];
    C[idx] = acc;
}

__global__ __launch_bounds__(256) void k_matsq(const float* __restrict__ A,
                                               float* __restrict__ C) {
    int idx = blockIdx.x * 256 + threadIdx.x;
    int r = idx >> 7, c = idx & 127;
    float acc = 0.f;
#pragma unroll
    for (int i = 0; i < 128; ++i) acc += A[r * 128 + i] * A[i * 128 + c];
    C[idx] = acc;
}

// ---- hierarchical boundary-scan helpers ----
__device__ __forceinline__ void load_rowhalf(const float* __restrict__ P, int r, int h,
                                             float* __restrict__ p) {
#pragma unroll
    for (int i4 = 0; i4 < 16; ++i4) {
        float4 v = *(const float4*)&P[r * 128 + h * 64 + i4 * 4];
        p[4 * i4] = v.x; p[4 * i4 + 1] = v.y; p[4 * i4 + 2] = v.z; p[4 * i4 + 3] = v.w;
    }
}
__device__ __forceinline__ float dot64(const float* __restrict__ p, const float* s) {
    float a0 = 0.f, a1 = 0.f, a2 = 0.f, a3 = 0.f;
#pragma unroll
    for (int i4 = 0; i4 < 16; ++i4) {
        float4 w = *(const float4*)&s[i4 * 4];
        a0 += p[4 * i4] * w.x;  a1 += p[4 * i4 + 1] * w.y;
        a2 += p[4 * i4 + 2] * w.z;  a3 += p[4 * i4 + 3] * w.w;
    }
    return (a0 + a1) + (a2 + a3);
}

// Generic affine scan: per block, zero-init scan over `count` inputs with matrix P.
__global__ __launch_bounds__(256, 1) void k_scan(const float* __restrict__ P,
                                                 const float* __restrict__ in,
                                                 float* __restrict__ partial,
                                                 float* __restrict__ terminal,
                                                 const int count) {
    const int bx = blockIdx.x;
    const int tid = threadIdx.x;
    const int r = tid & 127, h = tid >> 7;
    __shared__ __align__(16) float scur[128];
    __shared__ float pacc[256];
    float p[64];
    load_rowhalf(P, r, h, p);
    if (tid < 128) scur[tid] = 0.f;
    __syncthreads();
    const size_t base = (size_t)bx * count * 128;
    for (int k = 0; k < count; ++k) {
        if (tid < 128) partial[base + (size_t)k * 128 + tid] = scur[tid];
        pacc[tid] = dot64(p, &scur[h * 64]);
        __syncthreads();
        if (tid < 128) scur[tid] = pacc[tid] + pacc[tid + 128] + in[base + (size_t)k * 128 + tid];
        __syncthreads();
    }
    if (tid < 128) terminal[(size_t)bx * 128 + tid] = scur[tid];
}

// Generic fixup: out[k] = P^k * Sinit + q[k].
__global__ __launch_bounds__(256, 1) void k_fixupg(const float* __restrict__ P,
                                                   const float* __restrict__ Sinit,
                                                   const float* __restrict__ q,
                                                   float* __restrict__ out,
                                                   const int count) {
    const int bx = blockIdx.x;
    const int tid = threadIdx.x;
    const int r = tid & 127, h = tid >> 7;
    __shared__ __align__(16) float scur[128];
    __shared__ float pacc[256];
    float p[64];
    load_rowhalf(P, r, h, p);
    if (tid < 128) scur[tid] = Sinit[(size_t)bx * 128 + tid];
    __syncthreads();
    const size_t base = (size_t)bx * count * 128;
    for (int k = 0; k < count; ++k) {
        if (tid < 128) out[base + (size_t)k * 128 + tid] = scur[tid] + q[base + (size_t)k * 128 + tid];
        if (k == count - 1) break;
        pacc[tid] = dot64(p, &scur[h * 64]);
        __syncthreads();
        if (tid < 128) scur[tid] = pacc[tid] + pacc[tid + 128];
        __syncthreads();
    }
}

// Per-chunk local recurrence (CH=16 steps), 2-wave split; plane-major deltas.
__global__ __launch_bounds__(128, 1) void k_chunk_local(const float* __restrict__ deltas,
                                                        const float* __restrict__ m_y,
                                                        float* __restrict__ term) {
    const int b = blockIdx.x >> 8, j = blockIdx.x & 255;
    const int tid = threadIdx.x;
    const int o = tid & 63, h = tid >> 6;
    __shared__ __align__(16) float y1s[64];
    __shared__ __align__(16) float y2s[64];
    __shared__ float pacc[128];
    float m1[32], m2[32];
#pragma unroll
    for (int i4 = 0; i4 < 8; ++i4) {
        float4 v1 = *(const float4*)&m_y[o * 128 + h * 32 + i4 * 4];
        float4 v2 = *(const float4*)&m_y[o * 128 + 64 + h * 32 + i4 * 4];
        m1[4 * i4] = v1.x; m1[4 * i4 + 1] = v1.y; m1[4 * i4 + 2] = v1.z; m1[4 * i4 + 3] = v1.w;
        m2[4 * i4] = v2.x; m2[4 * i4 + 1] = v2.y; m2[4 * i4 + 2] = v2.z; m2[4 * i4 + 3] = v2.w;
    }
    if (tid < 64) { y1s[tid] = 0.f; y2s[tid] = 0.f; }
    __syncthreads();
    const float* dl = &deltas[((size_t)b * 64 + o) * LL + j * CH];
    for (int t = 0; t < CH; ++t) {
        float a0 = 0.f, a1 = 0.f, a2 = 0.f, a3 = 0.f;
#pragma unroll
        for (int i4 = 0; i4 < 8; ++i4) {
            float4 w1 = *(const float4*)&y1s[h * 32 + i4 * 4];
            float4 w2 = *(const float4*)&y2s[h * 32 + i4 * 4];
            a0 += m1[4 * i4] * w1.x + m2[4 * i4] * w2.x;
            a1 += m1[4 * i4 + 1] * w1.y + m2[4 * i4 + 1] * w2.y;
            a2 += m1[4 * i4 + 2] * w1.z + m2[4 * i4 + 2] * w2.z;
            a3 += m1[4 * i4 + 3] * w1.w + m2[4 * i4 + 3] * w2.w;
        }
        pacc[tid] = (a0 + a1) + (a2 + a3);
        __syncthreads();
        if (h == 0) {
            float outv = pacc[o] + pacc[o + 64] + dl[t];
            y2s[o] = y1s[o];
            y1s[o] = outv;
        }
        __syncthreads();
    }
    if (tid < 64) {
        term[((size_t)b * NCH + j) * 128 + o] = y1s[o];
        term[((size_t)b * NCH + j) * 128 + 64 + o] = y2s[o];
    }
}

// Per-chunk final recurrence with true initial states; writes row-major out.
__global__ __launch_bounds__(128, 1) void k_chunk_final(const float* __restrict__ deltas,
                                                        const float* __restrict__ m_y,
                                                        const float* __restrict__ sstate,
                                                        float* __restrict__ out) {
    const int b = blockIdx.x >> 8, j = blockIdx.x & 255;
    const int tid = threadIdx.x;
    const int o = tid & 63, h = tid >> 6;
    __shared__ __align__(16) float y1s[64];
    __shared__ __align__(16) float y2s[64];
    __shared__ float pacc[128];
    float m1[32], m2[32];
#pragma unroll
    for (int i4 = 0; i4 < 8; ++i4) {
        float4 v1 = *(const float4*)&m_y[o * 128 + h * 32 + i4 * 4];
        float4 v2 = *(const float4*)&m_y[o * 128 + 64 + h * 32 + i4 * 4];
        m1[4 * i4] = v1.x; m1[4 * i4 + 1] = v1.y; m1[4 * i4 + 2] = v1.z; m1[4 * i4 + 3] = v1.w;
        m2[4 * i4] = v2.x; m2[4 * i4 + 1] = v2.y; m2[4 * i4 + 2] = v2.z; m2[4 * i4 + 3] = v2.w;
    }
    if (tid < 64) {
        y1s[tid] = sstate[((size_t)b * NCH + j) * 128 + tid];
        y2s[tid] = sstate[((size_t)b * NCH + j) * 128 + 64 + tid];
    }
    __syncthreads();
    const float* dl = &deltas[((size_t)b * 64 + o) * LL + j * CH];
    const size_t obase = (((size_t)b * LL) + j * CH) * DD + o;
    for (int t = 0; t < CH; ++t) {
        float a0 = 0.f, a1 = 0.f, a2 = 0.f, a3 = 0.f;
#pragma unroll
        for (int i4 = 0; i4 < 8; ++i4) {
            float4 w1 = *(const float4*)&y1s[h * 32 + i4 * 4];
            float4 w2 = *(const float4*)&y2s[h * 32 + i4 * 4];
            a0 += m1[4 * i4] * w1.x + m2[4 * i4] * w2.x;
            a1 += m1[4 * i4 + 1] * w1.y + m2[4 * i4 + 1] * w2.y;
            a2 += m1[4 * i4 + 2] * w1.z + m2[4 * i4 + 2] * w2.z;
            a3 += m1[4 * i4 + 3] * w1.w + m2[4 * i4 + 3] * w2.w;
        }
        pacc[tid] = (a0 + a1) + (a2 + a3);
        __syncthreads();
        if (h == 0) {
            float outv = pacc[o] + pacc[o + 64] + dl[t];
            out[obase + (size_t)t * DD] = outv;
            y2s[o] = y1s[o];
            y1s[o] = outv;
        }
        __syncthreads();
    }
}

extern "C" void kernel_launch(void* const* d_in, const int* in_sizes, int n_in,
                              void* d_out, int out_size, void* d_ws, size_t ws_size,
                              hipStream_t stream) {
    const float* x        = (const float*)d_in[0];
    const float* m_y      = (const float*)d_in[1];
    const float* m_u      = (const float*)d_in[2];
    const float* m_phi    = (const float*)d_in[3];
    const float* eig_vals = (const float*)d_in[4];
    const float* eig_vecs = (const float*)d_in[5];
    float* out = (float*)d_out;

    char* ws = (char*)d_ws;
    size_t off = 0;
    auto alloc = [&](size_t bytes) -> void* {
        void* p = ws + off;
        off += (bytes + 255) & ~(size_t)255;
        return p;
    };
    float2* Vb   = (float2*)alloc((size_t)NN * KK * sizeof(float2));          // 1.6 MB
    uint*   Uxp  = (uint*)alloc((size_t)BB * 32 * NP * sizeof(uint));         // 4.2 MB
    uint*   Uyp  = (uint*)alloc((size_t)BB * 32 * NP * sizeof(uint));         // 4.2 MB
    uint*   Sb2  = (uint*)alloc((size_t)BB * 64 * NP * sizeof(uint));         // 8.5 MB
    float*  deltas = (float*)alloc((size_t)BB * 64 * LL * sizeof(float));     // 8.4 MB (plane-major)
    uint*   mp2  = (uint*)alloc((size_t)KT * 64 * 32 * sizeof(uint));         // 0.22 MB
    float2* twcg = (float2*)alloc((size_t)8192 * sizeof(float2));             // 64 KB
    float*  mats = (float*)alloc((size_t)4 * 128 * 128 * sizeof(float));
    float*  term = (float*)alloc((size_t)BB * NCH * 128 * sizeof(float));
    float*  sst  = (float*)alloc((size_t)BB * NCH * 128 * sizeof(float));
    float*  qbuf = (float*)alloc((size_t)BB * NCH * 128 * sizeof(float));
    float*  Qg   = (float*)alloc((size_t)BB * 16 * 128 * sizeof(float));
    float*  Sgt  = (float*)alloc((size_t)BB * 16 * 128 * sizeof(float));
    float*  dmy  = (float*)alloc((size_t)8 * 128 * sizeof(float));

    k_twiddle<<<dim3(16), dim3(512), 0, stream>>>(twcg);
    k_pack<<<dim3(216), dim3(256), 0, stream>>>(m_phi, m_u, mp2);
    k_fft_filters<<<dim3(24), dim3(256), 0, stream>>>(eig_vals, eig_vecs, twcg, Vb);
    k_fft_x2<<<dim3(256), dim3(512), 0, stream>>>(x, twcg, Uxp, Uyp);

    float* T1   = mats;
    float* T2   = mats + 16384;
    float* P16  = mats + 32768;
    float* P256 = mats + 49152;
    k_matsq1<<<dim3(64), dim3(256), 0, stream>>>(m_y, T1);   // M^2
    k_matsq<<<dim3(64), dim3(256), 0, stream>>>(T1, T2);     // M^4
    k_matsq<<<dim3(64), dim3(256), 0, stream>>>(T2, T1);     // M^8
    k_matsq<<<dim3(64), dim3(256), 0, stream>>>(T1, P16);    // M^16
    k_matsq<<<dim3(64), dim3(256), 0, stream>>>(P16, T1);    // M^32
    k_matsq<<<dim3(64), dim3(256), 0, stream>>>(T1, T2);     // M^64
    k_matsq<<<dim3(64), dim3(256), 0, stream>>>(T2, T1);     // M^128
    k_matsq<<<dim3(64), dim3(256), 0, stream>>>(T1, P256);   // M^256

    k_modulate7<<<dim3(129, 8), dim3(256), 0, stream>>>(Vb, Uxp, Uyp, mp2, Sb2, 0, 13, 0);
    k_modulate7<<<dim3(129, 8), dim3(256), 0, stream>>>(Vb, Uxp, Uyp, mp2, Sb2, 13, 14, 1);
    k_ifft2<<<dim3(256), dim3(512), 0, stream>>>(Sb2, twcg, deltas);

    k_chunk_local<<<dim3(2048), dim3(128), 0, stream>>>(deltas, m_y, term);
    k_scan<<<dim3(128), dim3(256), 0, stream>>>(P16, term, qbuf, Qg, 16);   // per (b,g<16)
    k_scan<<<dim3(8), dim3(256), 0, stream>>>(P256, Qg, Sgt, dmy, 16);      // per b -> group inits
    k_fixupg<<<dim3(128), dim3(256), 0, stream>>>(P16, Sgt, qbuf, sst, 16); // chunk inits
    k_chunk_final<<<dim3(2048), dim3(128), 0, stream>>>(deltas, m_y, sst, out);
}

// Round 17
// 218.374 us; speedup vs baseline: 1.4452x; 1.4452x over previous
//
#include <hip/hip_runtime.h>
#include <math.h>

#define BB 8
#define LL 4096
#define DD 64
#define KK 24
#define KT 27       // 24 spectral filters + 3 AR-U taps
#define NN 8192
#define LOGN 13
#define NP 4128     // padded half-spectrum rows per batch (129 tiles * 32)
#define NCH 256     // chunks per batch
#define CH 16       // timesteps per chunk
#define PAD 80      // LDS row pitch in u16 (40 dwords -> conflict-free b128 reads)

typedef unsigned int uint;
typedef unsigned short u16;
typedef __attribute__((ext_vector_type(8))) short bf16x8;
typedef __attribute__((ext_vector_type(4))) float f32x4;

__device__ __forceinline__ float bfl(uint u) {
    union { uint u; float f; } v; v.u = u << 16; return v.f;
}
__device__ __forceinline__ float bfh(uint u) {
    union { uint u; float f; } v; v.u = u & 0xFFFF0000u; return v.f;
}
__device__ __forceinline__ uint pk(float x) {
    union { float f; uint u; } v; v.f = x;
    return (v.u + 0x7FFFu + ((v.u >> 16) & 1u)) >> 16;
}
__device__ __forceinline__ float2 unpk2(uint u) {
    return make_float2(bfl(u), bfh(u));
}
__device__ __forceinline__ int br13(int v) { return (int)(__brev((uint)v) >> 19); }

// ---------------- FFT primitives, twiddles from a global L2-resident table ----------------
template<int NT>
__device__ __forceinline__ void fft_dif(float2* a, const float2* __restrict__ twc) {
    const int tid = threadIdx.x;
    for (int lh = LOGN - 1; lh >= 0; --lh) {
        const int half = 1 << lh;
#pragma unroll
        for (int bb = 0; bb < NN / 2 / NT; ++bb) {
            int t = tid + bb * NT;
            int j = t & (half - 1);
            int i0 = ((t >> lh) << (lh + 1)) + j;
            float2 u = a[i0], v = a[i0 + half];
            float2 w = twc[half + j];
            float cs = w.x, sn = w.y;
            float dx = u.x - v.x, dy = u.y - v.y;
            a[i0] = make_float2(u.x + v.x, u.y + v.y);
            a[i0 + half] = make_float2(dx * cs - dy * sn, dx * sn + dy * cs);
        }
        __syncthreads();
    }
}

template<int NT>
__device__ __forceinline__ void fft_dit(float2* a, const float2* __restrict__ twc) {
    const int tid = threadIdx.x;
    for (int lh = 0; lh < LOGN; ++lh) {
        const int half = 1 << lh;
#pragma unroll
        for (int bb = 0; bb < NN / 2 / NT; ++bb) {
            int t = tid + bb * NT;
            int j = t & (half - 1);
            int i0 = ((t >> lh) << (lh + 1)) + j;
            float2 u = a[i0], v = a[i0 + half];
            float2 w = twc[half + j];
            float cs = w.x, sn = -w.y;      // conjugate for inverse
            float wx = v.x * cs - v.y * sn;
            float wy = v.x * sn + v.y * cs;
            a[i0] = make_float2(u.x + wx, u.y + wy);
            a[i0 + half] = make_float2(u.x - wx, u.y - wy);
        }
        __syncthreads();
    }
}

// ---------------- kernels ----------------

// Fused: blocks 0..215 pack the 27 B-slabs; blocks 216..247 build the twiddle table.
__global__ __launch_bounds__(256) void k_packtw(const float* __restrict__ mphi,
                                                const float* __restrict__ mu,
                                                uint* __restrict__ mp2,
                                                float2* __restrict__ twc) {
    const int bx = blockIdx.x;
    if (bx < 216) {
        int idx = bx * 256 + threadIdx.x;
        if (idx >= KT * 2048) return;
        int k = idx >> 11;
        int rem = idx & 2047;
        int o = rem >> 5, cp = rem & 31;
        int c = cp * 2;
        uint v;
        if (k < KK) {
            v = pk(mphi[(k * 64 + c) * 64 + o]) | (pk(mphi[(k * 64 + c + 1) * 64 + o]) << 16);
        } else {
            int ku = k - KK;
            v = pk(mu[(o * 64 + c) * 3 + ku]) | (pk(mu[(o * 64 + c + 1) * 3 + ku]) << 16);
        }
        mp2[idx] = v;
    } else {
        int i = (bx - 216) * 256 + threadIdx.x;
        if (i >= 8192) return;
        if (i == 0) { twc[0] = make_float2(1.f, 0.f); return; }
        int lh = 31 - __builtin_clz((uint)i);
        int j = i - (1 << lh);
        float ang = -6.28318530717958647692f * (float)j / (float)(2 << lh);
        float sn, cs;
        __sincosf(ang, &sn, &cs);
        twc[i] = make_float2(cs, sn);
    }
}

// Fused FFT kernel: blocks 0..255 = signal FFTs (two real channels per complex
// FFT, plane-major U out); blocks 256..279 = filter FFTs -> Vb.
__global__ __launch_bounds__(512) void k_fft_all(const float* __restrict__ x,
                                                 const float* __restrict__ eig_vals,
                                                 const float* __restrict__ eig_vecs,
                                                 const float2* __restrict__ twc,
                                                 uint* __restrict__ Uxp,
                                                 uint* __restrict__ Uyp,
                                                 float2* __restrict__ Vb) {
    __shared__ float2 a[NN];
    const int tid = threadIdx.x;
    if (blockIdx.x < 256) {
        const int b = blockIdx.x & 7, cp = blockIdx.x >> 3;
        for (int l = tid; l < LL; l += 512)
            a[l] = *(const float2*)&x[((size_t)b * LL + l) * DD + 2 * cp];
        for (int l = LL + tid; l < NN; l += 512)
            a[l] = make_float2(0.f, 0.f);
        __syncthreads();
        fft_dif<512>(a, twc);
        const size_t plane = ((size_t)b * 32 + cp) * NP;
        for (int idx = tid; idx < 4097; idx += 512) {
            int r = (idx == 4096) ? 1 : 2 * idx;
            int fn = br13(r);
            int q = br13((8192 - fn) & 8191);
            float2 Z = a[r], W = a[q];
            float ucx = 0.5f * (Z.x + W.x), ucy = 0.5f * (Z.y - W.y);
            float upx = 0.5f * (Z.y + W.y), upy = 0.5f * (W.x - Z.x);
            Uxp[plane + idx] = pk(ucx) | (pk(upx) << 16);
            Uyp[plane + idx] = pk(ucy) | (pk(upy) << 16);
        }
        for (int idx = 4097 + tid; idx < NP; idx += 512) {
            Uxp[plane + idx] = 0;
            Uyp[plane + idx] = 0;
        }
    } else {
        const int k = blockIdx.x - 256;
        const float alpha = powf(eig_vals[k], 0.25f) * (1.0f / (float)NN);
        for (int t = tid; t < LL; t += 512)
            a[t] = make_float2(eig_vecs[t * KK + k] * alpha, 0.f);
        for (int t = LL + tid; t < NN; t += 512)
            a[t] = make_float2(0.f, 0.f);
        __syncthreads();
        fft_dif<512>(a, twc);
        for (int r = tid; r < NN; r += 512)
            Vb[(size_t)r * KK + k] = a[r];
    }
}

// MFMA modulate over 27 slabs (R12/R14-proven structure, PAD=80 rows).
__global__ __launch_bounds__(256) void k_modulate5(const float2* __restrict__ Vb,
                                                   const uint* __restrict__ Uxp,
                                                   const uint* __restrict__ Uyp,
                                                   const uint* __restrict__ mp2,
                                                   uint* __restrict__ Sb2) {
    __shared__ u16 Uxs[32][PAD];
    __shared__ u16 Uys[32][PAD];
    __shared__ u16 mpT[2][64][PAD];
    __shared__ float2 Vt[32][28];
    const int tid = threadIdx.x;
    const int pt = blockIdx.x;
    const int b  = blockIdx.y;
    const int p0 = pt * 32;

    for (int i = tid; i < 1024; i += 256) {
        int cp = i >> 5, row = i & 31;
        uint vx = Uxp[((size_t)b * 32 + cp) * NP + p0 + row];
        uint vy = Uyp[((size_t)b * 32 + cp) * NP + p0 + row];
        *(uint*)&Uxs[row][cp * 2] = vx;
        *(uint*)&Uys[row][cp * 2] = vy;
    }
    {
        int o = tid >> 2, seg = tid & 3;
        const uint4* src = (const uint4*)&mp2[(size_t)o * 32 + seg * 8];
        uint4 m0 = src[0], m1 = src[1];
        *(uint4*)&mpT[0][o][seg * 16] = m0;
        *(uint4*)&mpT[0][o][seg * 16 + 8] = m1;
    }
    for (int i = tid; i < 768; i += 256) {
        int pi = i / 24, kk = i - pi * 24;
        int pidx = p0 + pi; if (pidx > 4096) pidx = 4096;
        int r = (pidx == 4096) ? 1 : 2 * pidx;
        Vt[pi][kk] = Vb[(size_t)r * KK + kk];
    }
    for (int pi = tid; pi < 32; pi += 256) {
        int pidx = p0 + pi; if (pidx > 4096) pidx = 4096;
        int r = (pidx == 4096) ? 1 : 2 * pidx;
        int f = br13(r);
        const float invN = 1.f / 8192.f;
        float ph = -6.28318530717958647692f * (float)f * invN;
        float s1, c1, s2, c2;
        __sincosf(ph, &s1, &c1);
        __sincosf(2.f * ph, &s2, &c2);
        Vt[pi][24] = make_float2(invN, 0.f);
        Vt[pi][25] = make_float2(c1 * invN, s1 * invN);
        Vt[pi][26] = make_float2(c2 * invN, s2 * invN);
    }
    __syncthreads();

    const int lane = tid & 63, w = tid >> 6;
    const int rt = w & 1, chalf = w >> 1;
    const int lrow = lane & 15, lk = lane >> 4;
    const u16* axp = &Uxs[rt * 16 + lrow][lk * 8];
    const u16* ayp = &Uys[rt * 16 + lrow][lk * 8];

    float Sx0[4] = {0.f, 0.f, 0.f, 0.f}, Sy0[4] = {0.f, 0.f, 0.f, 0.f};
    float Sx1[4] = {0.f, 0.f, 0.f, 0.f}, Sy1[4] = {0.f, 0.f, 0.f, 0.f};

    for (int k = 0; k < KT; ++k) {
        const int cur = k & 1;
        bf16x8 ax0 = *(const bf16x8*)(axp);
        bf16x8 ax1 = *(const bf16x8*)(axp + 32);
        bf16x8 ay0 = *(const bf16x8*)(ayp);
        bf16x8 ay1 = *(const bf16x8*)(ayp + 32);
        const u16* bp0 = &mpT[cur][chalf * 32 + lrow][lk * 8];
        const u16* bp1 = &mpT[cur][chalf * 32 + 16 + lrow][lk * 8];
        bf16x8 b00 = *(const bf16x8*)(bp0);
        bf16x8 b01 = *(const bf16x8*)(bp0 + 32);
        bf16x8 b10 = *(const bf16x8*)(bp1);
        bf16x8 b11 = *(const bf16x8*)(bp1 + 32);
        float2 v0 = Vt[rt * 16 + lk * 4 + 0][k];
        float2 v1 = Vt[rt * 16 + lk * 4 + 1][k];
        float2 v2 = Vt[rt * 16 + lk * 4 + 2][k];
        float2 v3 = Vt[rt * 16 + lk * 4 + 3][k];
        if (k + 1 < KT) {
            int o = tid >> 2, seg = tid & 3;
            const uint4* src = (const uint4*)&mp2[((size_t)(k + 1) * 64 + o) * 32 + seg * 8];
            uint4 m0 = src[0], m1 = src[1];
            *(uint4*)&mpT[cur ^ 1][o][seg * 16] = m0;
            *(uint4*)&mpT[cur ^ 1][o][seg * 16 + 8] = m1;
        }
        f32x4 z = {0.f, 0.f, 0.f, 0.f};
        f32x4 Wx0 = __builtin_amdgcn_mfma_f32_16x16x32_bf16(ax0, b00, z, 0, 0, 0);
        Wx0 = __builtin_amdgcn_mfma_f32_16x16x32_bf16(ax1, b01, Wx0, 0, 0, 0);
        f32x4 Wy0 = __builtin_amdgcn_mfma_f32_16x16x32_bf16(ay0, b00, z, 0, 0, 0);
        Wy0 = __builtin_amdgcn_mfma_f32_16x16x32_bf16(ay1, b01, Wy0, 0, 0, 0);
        f32x4 Wx1 = __builtin_amdgcn_mfma_f32_16x16x32_bf16(ax0, b10, z, 0, 0, 0);
        Wx1 = __builtin_amdgcn_mfma_f32_16x16x32_bf16(ax1, b11, Wx1, 0, 0, 0);
        f32x4 Wy1 = __builtin_amdgcn_mfma_f32_16x16x32_bf16(ay0, b10, z, 0, 0, 0);
        Wy1 = __builtin_amdgcn_mfma_f32_16x16x32_bf16(ay1, b11, Wy1, 0, 0, 0);
        Sx0[0] += v0.x * Wx0[0] - v0.y * Wy0[0];  Sy0[0] += v0.x * Wy0[0] + v0.y * Wx0[0];
        Sx0[1] += v1.x * Wx0[1] - v1.y * Wy0[1];  Sy0[1] += v1.x * Wy0[1] + v1.y * Wx0[1];
        Sx0[2] += v2.x * Wx0[2] - v2.y * Wy0[2];  Sy0[2] += v2.x * Wy0[2] + v2.y * Wx0[2];
        Sx0[3] += v3.x * Wx0[3] - v3.y * Wy0[3];  Sy0[3] += v3.x * Wy0[3] + v3.y * Wx0[3];
        Sx1[0] += v0.x * Wx1[0] - v0.y * Wy1[0];  Sy1[0] += v0.x * Wy1[0] + v0.y * Wx1[0];
        Sx1[1] += v1.x * Wx1[1] - v1.y * Wy1[1];  Sy1[1] += v1.x * Wy1[1] + v1.y * Wx1[1];
        Sx1[2] += v2.x * Wx1[2] - v2.y * Wy1[2];  Sy1[2] += v2.x * Wy1[2] + v2.y * Wx1[2];
        Sx1[3] += v3.x * Wx1[3] - v3.y * Wy1[3];  Sy1[3] += v3.x * Wy1[3] + v3.y * Wx1[3];
        __syncthreads();
    }
    const int rbase = rt * 16 + lk * 4;
    const int o0 = chalf * 32 + lrow;
    const size_t pl0 = ((size_t)b * 64 + o0) * NP + p0 + rbase;
    const size_t pl1 = ((size_t)b * 64 + o0 + 16) * NP + p0 + rbase;
#pragma unroll
    for (int j = 0; j < 4; ++j) {
        Sb2[pl0 + j] = pk(Sx0[j]) | (pk(Sy0[j]) << 16);
        Sb2[pl1 + j] = pk(Sx1[j]) | (pk(Sy1[j]) << 16);
    }
}

// Two output channels per inverse FFT; plane-major S in, plane-major deltas out.
__global__ __launch_bounds__(512) void k_ifft2(const uint* __restrict__ Sb2,
                                               const float2* __restrict__ twc,
                                               float* __restrict__ deltas) {
    __shared__ float2 a[NN];
    const int b = blockIdx.x & 7, op = blockIdx.x >> 3;
    const int tid = threadIdx.x;
    const uint* s0 = &Sb2[((size_t)b * 64 + op * 2) * NP];
    const uint* s1 = &Sb2[((size_t)b * 64 + op * 2 + 1) * NP];
    for (int idx = tid; idx < 4097; idx += 512) {
        int r = (idx == 4096) ? 1 : 2 * idx;
        float2 A = unpk2(s0[idx]), B = unpk2(s1[idx]);
        a[r] = make_float2(A.x - B.y, A.y + B.x);
        int fn = br13(r);
        int q = br13((8192 - fn) & 8191);
        if (q != r) a[q] = make_float2(A.x + B.y, B.x - A.y);
    }
    __syncthreads();
    fft_dit<512>(a, twc);
    float* d0 = &deltas[((size_t)b * 64 + op * 2) * LL];
    float* d1 = &deltas[((size_t)b * 64 + op * 2 + 1) * LL];
    for (int l = tid; l < LL; l += 512) {
        d0[l] = a[l].x;
        d1[l] = a[l].y;
    }
}

// First squaring with companion matrix built on the fly from m_y.
__global__ __launch_bounds__(256) void k_matsq1(const float* __restrict__ m_y,
                                                float* __restrict__ C) {
    int idx = blockIdx.x * 256 + threadIdx.x;
    int r = idx >> 7, c = idx & 127;
    if (r >= 64) { C[idx] = m_y[(r - 64) * 128 + c]; return; }
    float acc = (c < 64) ? m_y[r * 128 + 64 + c] : 0.f;
#pragma unroll
    for (int i = 0; i < 64; ++i) acc += m_y[r * 128 + i] * m_y[i * 128 + c];
    C[idx] = acc;
}

__global__ __launch_bounds__(256) void k_matsq(const float* __restrict__ A,
                                               float* __restrict__ C) {
    int idx = blockIdx.x * 256 + threadIdx.x;
    int r = idx >> 7, c = idx & 127;
    float acc = 0.f;
#pragma unroll
    for (int i = 0; i < 128; ++i) acc += A[r * 128 + i] * A[i * 128 + c];
    C[idx] = acc;
}

// ---- hierarchical boundary-scan helpers ----
__device__ __forceinline__ void load_rowhalf(const float* __restrict__ P, int r, int h,
                                             float* __restrict__ p) {
#pragma unroll
    for (int i4 = 0; i4 < 16; ++i4) {
        float4 v = *(const float4*)&P[r * 128 + h * 64 + i4 * 4];
        p[4 * i4] = v.x; p[4 * i4 + 1] = v.y; p[4 * i4 + 2] = v.z; p[4 * i4 + 3] = v.w;
    }
}
__device__ __forceinline__ float dot64(const float* __restrict__ p, const float* s) {
    float a0 = 0.f, a1 = 0.f, a2 = 0.f, a3 = 0.f;
#pragma unroll
    for (int i4 = 0; i4 < 16; ++i4) {
        float4 w = *(const float4*)&s[i4 * 4];
        a0 += p[4 * i4] * w.x;  a1 += p[4 * i4 + 1] * w.y;
        a2 += p[4 * i4 + 2] * w.z;  a3 += p[4 * i4 + 3] * w.w;
    }
    return (a0 + a1) + (a2 + a3);
}

// Generic affine scan: per block, zero-init scan over `count` inputs with matrix P.
__global__ __launch_bounds__(256, 1) void k_scan(const float* __restrict__ P,
                                                 const float* __restrict__ in,
                                                 float* __restrict__ partial,
                                                 float* __restrict__ terminal,
                                                 const int count) {
    const int bx = blockIdx.x;
    const int tid = threadIdx.x;
    const int r = tid & 127, h = tid >> 7;
    __shared__ __align__(16) float scur[128];
    __shared__ float pacc[256];
    float p[64];
    load_rowhalf(P, r, h, p);
    if (tid < 128) scur[tid] = 0.f;
    __syncthreads();
    const size_t base = (size_t)bx * count * 128;
    for (int k = 0; k < count; ++k) {
        if (tid < 128) partial[base + (size_t)k * 128 + tid] = scur[tid];
        pacc[tid] = dot64(p, &scur[h * 64]);
        __syncthreads();
        if (tid < 128) scur[tid] = pacc[tid] + pacc[tid + 128] + in[base + (size_t)k * 128 + tid];
        __syncthreads();
    }
    if (tid < 128) terminal[(size_t)bx * 128 + tid] = scur[tid];
}

// Generic fixup: out[k] = P^k * Sinit + q[k].
__global__ __launch_bounds__(256, 1) void k_fixupg(const float* __restrict__ P,
                                                   const float* __restrict__ Sinit,
                                                   const float* __restrict__ q,
                                                   float* __restrict__ out,
                                                   const int count) {
    const int bx = blockIdx.x;
    const int tid = threadIdx.x;
    const int r = tid & 127, h = tid >> 7;
    __shared__ __align__(16) float scur[128];
    __shared__ float pacc[256];
    float p[64];
    load_rowhalf(P, r, h, p);
    if (tid < 128) scur[tid] = Sinit[(size_t)bx * 128 + tid];
    __syncthreads();
    const size_t base = (size_t)bx * count * 128;
    for (int k = 0; k < count; ++k) {
        if (tid < 128) out[base + (size_t)k * 128 + tid] = scur[tid] + q[base + (size_t)k * 128 + tid];
        if (k == count - 1) break;
        pacc[tid] = dot64(p, &scur[h * 64]);
        __syncthreads();
        if (tid < 128) scur[tid] = pacc[tid] + pacc[tid + 128];
        __syncthreads();
    }
}

// Per-chunk local recurrence (CH=16 steps), 2-wave split; plane-major deltas.
__global__ __launch_bounds__(128, 1) void k_chunk_local(const float* __restrict__ deltas,
                                                        const float* __restrict__ m_y,
                                                        float* __restrict__ term) {
    const int b = blockIdx.x >> 8, j = blockIdx.x & 255;
    const int tid = threadIdx.x;
    const int o = tid & 63, h = tid >> 6;
    __shared__ __align__(16) float y1s[64];
    __shared__ __align__(16) float y2s[64];
    __shared__ float pacc[128];
    float m1[32], m2[32];
#pragma unroll
    for (int i4 = 0; i4 < 8; ++i4) {
        float4 v1 = *(const float4*)&m_y[o * 128 + h * 32 + i4 * 4];
        float4 v2 = *(const float4*)&m_y[o * 128 + 64 + h * 32 + i4 * 4];
        m1[4 * i4] = v1.x; m1[4 * i4 + 1] = v1.y; m1[4 * i4 + 2] = v1.z; m1[4 * i4 + 3] = v1.w;
        m2[4 * i4] = v2.x; m2[4 * i4 + 1] = v2.y; m2[4 * i4 + 2] = v2.z; m2[4 * i4 + 3] = v2.w;
    }
    if (tid < 64) { y1s[tid] = 0.f; y2s[tid] = 0.f; }
    __syncthreads();
    const float* dl = &deltas[((size_t)b * 64 + o) * LL + j * CH];
    for (int t = 0; t < CH; ++t) {
        float a0 = 0.f, a1 = 0.f, a2 = 0.f, a3 = 0.f;
#pragma unroll
        for (int i4 = 0; i4 < 8; ++i4) {
            float4 w1 = *(const float4*)&y1s[h * 32 + i4 * 4];
            float4 w2 = *(const float4*)&y2s[h * 32 + i4 * 4];
            a0 += m1[4 * i4] * w1.x + m2[4 * i4] * w2.x;
            a1 += m1[4 * i4 + 1] * w1.y + m2[4 * i4 + 1] * w2.y;
            a2 += m1[4 * i4 + 2] * w1.z + m2[4 * i4 + 2] * w2.z;
            a3 += m1[4 * i4 + 3] * w1.w + m2[4 * i4 + 3] * w2.w;
        }
        pacc[tid] = (a0 + a1) + (a2 + a3);
        __syncthreads();
        if (h == 0) {
            float outv = pacc[o] + pacc[o + 64] + dl[t];
            y2s[o] = y1s[o];
            y1s[o] = outv;
        }
        __syncthreads();
    }
    if (tid < 64) {
        term[((size_t)b * NCH + j) * 128 + o] = y1s[o];
        term[((size_t)b * NCH + j) * 128 + 64 + o] = y2s[o];
    }
}

// Per-chunk final recurrence with true initial states; writes row-major out.
__global__ __launch_bounds__(128, 1) void k_chunk_final(const float* __restrict__ deltas,
                                                        const float* __restrict__ m_y,
                                                        const float* __restrict__ sstate,
                                                        float* __restrict__ out) {
    const int b = blockIdx.x >> 8, j = blockIdx.x & 255;
    const int tid = threadIdx.x;
    const int o = tid & 63, h = tid >> 6;
    __shared__ __align__(16) float y1s[64];
    __shared__ __align__(16) float y2s[64];
    __shared__ float pacc[128];
    float m1[32], m2[32];
#pragma unroll
    for (int i4 = 0; i4 < 8; ++i4) {
        float4 v1 = *(const float4*)&m_y[o * 128 + h * 32 + i4 * 4];
        float4 v2 = *(const float4*)&m_y[o * 128 + 64 + h * 32 + i4 * 4];
        m1[4 * i4] = v1.x; m1[4 * i4 + 1] = v1.y; m1[4 * i4 + 2] = v1.z; m1[4 * i4 + 3] = v1.w;
        m2[4 * i4] = v2.x; m2[4 * i4 + 1] = v2.y; m2[4 * i4 + 2] = v2.z; m2[4 * i4 + 3] = v2.w;
    }
    if (tid < 64) {
        y1s[tid] = sstate[((size_t)b * NCH + j) * 128 + tid];
        y2s[tid] = sstate[((size_t)b * NCH + j) * 128 + 64 + tid];
    }
    __syncthreads();
    const float* dl = &deltas[((size_t)b * 64 + o) * LL + j * CH];
    const size_t obase = (((size_t)b * LL) + j * CH) * DD + o;
    for (int t = 0; t < CH; ++t) {
        float a0 = 0.f, a1 = 0.f, a2 = 0.f, a3 = 0.f;
#pragma unroll
        for (int i4 = 0; i4 < 8; ++i4) {
            float4 w1 = *(const float4*)&y1s[h * 32 + i4 * 4];
            float4 w2 = *(const float4*)&y2s[h * 32 + i4 * 4];
            a0 += m1[4 * i4] * w1.x + m2[4 * i4] * w2.x;
            a1 += m1[4 * i4 + 1] * w1.y + m2[4 * i4 + 1] * w2.y;
            a2 += m1[4 * i4 + 2] * w1.z + m2[4 * i4 + 2] * w2.z;
            a3 += m1[4 * i4 + 3] * w1.w + m2[4 * i4 + 3] * w2.w;
        }
        pacc[tid] = (a0 + a1) + (a2 + a3);
        __syncthreads();
        if (h == 0) {
            float outv = pacc[o] + pacc[o + 64] + dl[t];
            out[obase + (size_t)t * DD] = outv;
            y2s[o] = y1s[o];
            y1s[o] = outv;
        }
        __syncthreads();
    }
}

extern "C" void kernel_launch(void* const* d_in, const int* in_sizes, int n_in,
                              void* d_out, int out_size, void* d_ws, size_t ws_size,
                              hipStream_t stream) {
    const float* x        = (const float*)d_in[0];
    const float* m_y      = (const float*)d_in[1];
    const float* m_u      = (const float*)d_in[2];
    const float* m_phi    = (const float*)d_in[3];
    const float* eig_vals = (const float*)d_in[4];
    const float* eig_vecs = (const float*)d_in[5];
    float* out = (float*)d_out;

    char* ws = (char*)d_ws;
    size_t off = 0;
    auto alloc = [&](size_t bytes) -> void* {
        void* p = ws + off;
        off += (bytes + 255) & ~(size_t)255;
        return p;
    };
    float2* Vb   = (float2*)alloc((size_t)NN * KK * sizeof(float2));          // 1.6 MB
    uint*   Uxp  = (uint*)alloc((size_t)BB * 32 * NP * sizeof(uint));         // 4.2 MB
    uint*   Uyp  = (uint*)alloc((size_t)BB * 32 * NP * sizeof(uint));         // 4.2 MB
    uint*   Sb2  = (uint*)alloc((size_t)BB * 64 * NP * sizeof(uint));         // 8.5 MB
    float*  deltas = (float*)alloc((size_t)BB * 64 * LL * sizeof(float));     // 8.4 MB (plane-major)
    uint*   mp2  = (uint*)alloc((size_t)KT * 64 * 32 * sizeof(uint));         // 0.22 MB
    float2* twcg = (float2*)alloc((size_t)8192 * sizeof(float2));             // 64 KB
    float*  mats = (float*)alloc((size_t)4 * 128 * 128 * sizeof(float));
    float*  term = (float*)alloc((size_t)BB * NCH * 128 * sizeof(float));
    float*  sst  = (float*)alloc((size_t)BB * NCH * 128 * sizeof(float));
    float*  qbuf = (float*)alloc((size_t)BB * NCH * 128 * sizeof(float));
    float*  Qg   = (float*)alloc((size_t)BB * 16 * 128 * sizeof(float));
    float*  Sgt  = (float*)alloc((size_t)BB * 16 * 128 * sizeof(float));
    float*  dmy  = (float*)alloc((size_t)8 * 128 * sizeof(float));

    k_packtw<<<dim3(248), dim3(256), 0, stream>>>(m_phi, m_u, mp2, twcg);
    k_fft_all<<<dim3(280), dim3(512), 0, stream>>>(x, eig_vals, eig_vecs, twcg, Uxp, Uyp, Vb);

    float* T1   = mats;
    float* T2   = mats + 16384;
    float* P16  = mats + 32768;
    float* P256 = mats + 49152;
    k_matsq1<<<dim3(64), dim3(256), 0, stream>>>(m_y, T1);   // M^2
    k_matsq<<<dim3(64), dim3(256), 0, stream>>>(T1, T2);     // M^4
    k_matsq<<<dim3(64), dim3(256), 0, stream>>>(T2, T1);     // M^8
    k_matsq<<<dim3(64), dim3(256), 0, stream>>>(T1, P16);    // M^16
    k_matsq<<<dim3(64), dim3(256), 0, stream>>>(P16, T1);    // M^32
    k_matsq<<<dim3(64), dim3(256), 0, stream>>>(T1, T2);     // M^64
    k_matsq<<<dim3(64), dim3(256), 0, stream>>>(T2, T1);     // M^128
    k_matsq<<<dim3(64), dim3(256), 0, stream>>>(T1, P256);   // M^256

    k_modulate5<<<dim3(129, 8), dim3(256), 0, stream>>>(Vb, Uxp, Uyp, mp2, Sb2);
    k_ifft2<<<dim3(256), dim3(512), 0, stream>>>(Sb2, twcg, deltas);

    k_chunk_local<<<dim3(2048), dim3(128), 0, stream>>>(deltas, m_y, term);
    k_scan<<<dim3(128), dim3(256), 0, stream>>>(P16, term, qbuf, Qg, 16);   // per (b,g<16)
    k_scan<<<dim3(8), dim3(256), 0, stream>>>(P256, Qg, Sgt, dmy, 16);      // per b -> group inits
    k_fixupg<<<dim3(128), dim3(256), 0, stream>>>(P16, Sgt, qbuf, sst, 16); // chunk inits
    k_chunk_final<<<dim3(2048), dim3(128), 0, stream>>>(deltas, m_y, sst, out);
}

// Round 18
// 203.353 us; speedup vs baseline: 1.5519x; 1.0739x over previous
//
#include <hip/hip_runtime.h>
#include <math.h>

#define BB 8
#define LL 4096
#define DD 64
#define KK 24
#define KT 27       // 24 spectral filters + 3 AR-U taps
#define NN 8192
#define LOGN 13
#define NP 4128     // padded half-spectrum rows per batch (129 tiles * 32)
#define NCH 256     // chunks per batch
#define CH 16       // timesteps per chunk
#define PAD 80      // LDS row pitch in u16 (40 dwords -> conflict-free b128 reads)

typedef unsigned int uint;
typedef unsigned short u16;
typedef __attribute__((ext_vector_type(8))) short bf16x8;
typedef __attribute__((ext_vector_type(4))) float f32x4;

__device__ __forceinline__ float bfl(uint u) {
    union { uint u; float f; } v; v.u = u << 16; return v.f;
}
__device__ __forceinline__ float bfh(uint u) {
    union { uint u; float f; } v; v.u = u & 0xFFFF0000u; return v.f;
}
__device__ __forceinline__ uint pk(float x) {
    union { float f; uint u; } v; v.f = x;
    return (v.u + 0x7FFFu + ((v.u >> 16) & 1u)) >> 16;
}
__device__ __forceinline__ float2 unpk2(uint u) {
    return make_float2(bfl(u), bfh(u));
}
__device__ __forceinline__ int br13(int v) { return (int)(__brev((uint)v) >> 19); }
__device__ __forceinline__ float2 cmulf(float2 a, float2 w) {          // a*w
    return make_float2(a.x * w.x - a.y * w.y, a.x * w.y + a.y * w.x);
}
__device__ __forceinline__ float2 cmulcf(float2 a, float2 w) {         // a*conj(w)
    return make_float2(a.x * w.x + a.y * w.y, a.y * w.x - a.x * w.y);
}

// ---------------- FFT primitives: fused radix-2 stage pairs (7 LDS passes) ----------------
// Forward DIF, natural in -> bit-reversed out. Fused stages (lh, lh-1).
template<int NT>
__device__ __forceinline__ void fft_dif(float2* a, const float2* __restrict__ twc) {
    const int tid = threadIdx.x;
#pragma unroll
    for (int lh = LOGN - 1; lh >= 2; lh -= 2) {
        const int half = 1 << lh, q = half >> 1;
#pragma unroll
        for (int g = 0; g < NN / 4 / NT; ++g) {
            int gg = tid + g * NT;
            int j = gg & (q - 1);
            int B = (gg >> (lh - 1)) << (lh + 1);
            int e0 = B + j;
            float2 u0 = a[e0], u1 = a[e0 + q], u2 = a[e0 + half], u3 = a[e0 + half + q];
            // outer stage lh
            float2 t0 = make_float2(u0.x + u2.x, u0.y + u2.y);
            float2 t2 = cmulf(make_float2(u0.x - u2.x, u0.y - u2.y), twc[half + j]);
            float2 t1 = make_float2(u1.x + u3.x, u1.y + u3.y);
            float2 t3 = cmulf(make_float2(u1.x - u3.x, u1.y - u3.y), twc[half + j + q]);
            // inner stage lh-1
            float2 wq = twc[q + j];
            a[e0]            = make_float2(t0.x + t1.x, t0.y + t1.y);
            a[e0 + q]        = cmulf(make_float2(t0.x - t1.x, t0.y - t1.y), wq);
            a[e0 + half]     = make_float2(t2.x + t3.x, t2.y + t3.y);
            a[e0 + half + q] = cmulf(make_float2(t2.x - t3.x, t2.y - t3.y), wq);
        }
        __syncthreads();
    }
    // final stage lh = 0 (twiddle = 1)
#pragma unroll
    for (int g = 0; g < NN / 2 / NT; ++g) {
        int t = tid + g * NT;
        float2 u = a[2 * t], v = a[2 * t + 1];
        a[2 * t]     = make_float2(u.x + v.x, u.y + v.y);
        a[2 * t + 1] = make_float2(u.x - v.x, u.y - v.y);
    }
    __syncthreads();
}

// Inverse DIT, bit-reversed in -> natural out, NO 1/N scale. Fused stages (lh, lh+1).
template<int NT>
__device__ __forceinline__ void fft_dit(float2* a, const float2* __restrict__ twc) {
    const int tid = threadIdx.x;
    // stage lh = 0 (twiddle = 1)
#pragma unroll
    for (int g = 0; g < NN / 2 / NT; ++g) {
        int t = tid + g * NT;
        float2 u = a[2 * t], v = a[2 * t + 1];
        a[2 * t]     = make_float2(u.x + v.x, u.y + v.y);
        a[2 * t + 1] = make_float2(u.x - v.x, u.y - v.y);
    }
    __syncthreads();
#pragma unroll
    for (int lh = 1; lh < LOGN; lh += 2) {
        const int half = 1 << lh;
#pragma unroll
        for (int g = 0; g < NN / 4 / NT; ++g) {
            int gg = tid + g * NT;
            int j = gg & (half - 1);
            int B = (gg >> lh) << (lh + 2);
            int e0 = B + j;
            float2 u0 = a[e0], u1 = a[e0 + half], u2 = a[e0 + 2 * half], u3 = a[e0 + 3 * half];
            // inner stage lh
            float2 w = twc[half + j];
            float2 v1 = cmulcf(u1, w);
            float2 v3 = cmulcf(u3, w);
            float2 t0 = make_float2(u0.x + v1.x, u0.y + v1.y);
            float2 t1 = make_float2(u0.x - v1.x, u0.y - v1.y);
            float2 t2 = make_float2(u2.x + v3.x, u2.y + v3.y);
            float2 t3 = make_float2(u2.x - v3.x, u2.y - v3.y);
            // outer stage lh+1
            float2 w2 = twc[2 * half + j];
            float2 w3 = twc[2 * half + j + half];
            float2 s2 = cmulcf(t2, w2);
            float2 s3 = cmulcf(t3, w3);
            a[e0]            = make_float2(t0.x + s2.x, t0.y + s2.y);
            a[e0 + 2 * half] = make_float2(t0.x - s2.x, t0.y - s2.y);
            a[e0 + half]     = make_float2(t1.x + s3.x, t1.y + s3.y);
            a[e0 + 3 * half] = make_float2(t1.x - s3.x, t1.y - s3.y);
        }
        __syncthreads();
    }
}

// ---------------- kernels ----------------

// Fused: blocks 0..215 pack the 27 B-slabs; blocks 216..247 build the twiddle table.
__global__ __launch_bounds__(256) void k_packtw(const float* __restrict__ mphi,
                                                const float* __restrict__ mu,
                                                uint* __restrict__ mp2,
                                                float2* __restrict__ twc) {
    const int bx = blockIdx.x;
    if (bx < 216) {
        int idx = bx * 256 + threadIdx.x;
        if (idx >= KT * 2048) return;
        int k = idx >> 11;
        int rem = idx & 2047;
        int o = rem >> 5, cp = rem & 31;
        int c = cp * 2;
        uint v;
        if (k < KK) {
            v = pk(mphi[(k * 64 + c) * 64 + o]) | (pk(mphi[(k * 64 + c + 1) * 64 + o]) << 16);
        } else {
            int ku = k - KK;
            v = pk(mu[(o * 64 + c) * 3 + ku]) | (pk(mu[(o * 64 + c + 1) * 3 + ku]) << 16);
        }
        mp2[idx] = v;
    } else {
        int i = (bx - 216) * 256 + threadIdx.x;
        if (i >= 8192) return;
        if (i == 0) { twc[0] = make_float2(1.f, 0.f); return; }
        int lh = 31 - __builtin_clz((uint)i);
        int j = i - (1 << lh);
        float ang = -6.28318530717958647692f * (float)j / (float)(2 << lh);
        float sn, cs;
        __sincosf(ang, &sn, &cs);
        twc[i] = make_float2(cs, sn);
    }
}

// Fused FFT kernel: blocks 0..255 = signal FFTs (two real channels per complex
// FFT, plane-major U out); blocks 256..279 = filter FFTs -> Vb.
__global__ __launch_bounds__(512) void k_fft_all(const float* __restrict__ x,
                                                 const float* __restrict__ eig_vals,
                                                 const float* __restrict__ eig_vecs,
                                                 const float2* __restrict__ twc,
                                                 uint* __restrict__ Uxp,
                                                 uint* __restrict__ Uyp,
                                                 float2* __restrict__ Vb) {
    __shared__ float2 a[NN];
    const int tid = threadIdx.x;
    if (blockIdx.x < 256) {
        const int b = blockIdx.x & 7, cp = blockIdx.x >> 3;
        for (int l = tid; l < LL; l += 512)
            a[l] = *(const float2*)&x[((size_t)b * LL + l) * DD + 2 * cp];
        for (int l = LL + tid; l < NN; l += 512)
            a[l] = make_float2(0.f, 0.f);
        __syncthreads();
        fft_dif<512>(a, twc);
        const size_t plane = ((size_t)b * 32 + cp) * NP;
        for (int idx = tid; idx < 4097; idx += 512) {
            int r = (idx == 4096) ? 1 : 2 * idx;
            int fn = br13(r);
            int q = br13((8192 - fn) & 8191);
            float2 Z = a[r], W = a[q];
            float ucx = 0.5f * (Z.x + W.x), ucy = 0.5f * (Z.y - W.y);
            float upx = 0.5f * (Z.y + W.y), upy = 0.5f * (W.x - Z.x);
            Uxp[plane + idx] = pk(ucx) | (pk(upx) << 16);
            Uyp[plane + idx] = pk(ucy) | (pk(upy) << 16);
        }
        for (int idx = 4097 + tid; idx < NP; idx += 512) {
            Uxp[plane + idx] = 0;
            Uyp[plane + idx] = 0;
        }
    } else {
        const int k = blockIdx.x - 256;
        const float alpha = powf(eig_vals[k], 0.25f) * (1.0f / (float)NN);
        for (int t = tid; t < LL; t += 512)
            a[t] = make_float2(eig_vecs[t * KK + k] * alpha, 0.f);
        for (int t = LL + tid; t < NN; t += 512)
            a[t] = make_float2(0.f, 0.f);
        __syncthreads();
        fft_dif<512>(a, twc);
        for (int r = tid; r < NN; r += 512)
            Vb[(size_t)r * KK + k] = a[r];
    }
}

// MFMA modulate over 27 slabs (R12/R14-proven structure, PAD=80 rows).
__global__ __launch_bounds__(256) void k_modulate5(const float2* __restrict__ Vb,
                                                   const uint* __restrict__ Uxp,
                                                   const uint* __restrict__ Uyp,
                                                   const uint* __restrict__ mp2,
                                                   uint* __restrict__ Sb2) {
    __shared__ u16 Uxs[32][PAD];
    __shared__ u16 Uys[32][PAD];
    __shared__ u16 mpT[2][64][PAD];
    __shared__ float2 Vt[32][28];
    const int tid = threadIdx.x;
    const int pt = blockIdx.x;
    const int b  = blockIdx.y;
    const int p0 = pt * 32;

    for (int i = tid; i < 1024; i += 256) {
        int cp = i >> 5, row = i & 31;
        uint vx = Uxp[((size_t)b * 32 + cp) * NP + p0 + row];
        uint vy = Uyp[((size_t)b * 32 + cp) * NP + p0 + row];
        *(uint*)&Uxs[row][cp * 2] = vx;
        *(uint*)&Uys[row][cp * 2] = vy;
    }
    {
        int o = tid >> 2, seg = tid & 3;
        const uint4* src = (const uint4*)&mp2[(size_t)o * 32 + seg * 8];
        uint4 m0 = src[0], m1 = src[1];
        *(uint4*)&mpT[0][o][seg * 16] = m0;
        *(uint4*)&mpT[0][o][seg * 16 + 8] = m1;
    }
    for (int i = tid; i < 768; i += 256) {
        int pi = i / 24, kk = i - pi * 24;
        int pidx = p0 + pi; if (pidx > 4096) pidx = 4096;
        int r = (pidx == 4096) ? 1 : 2 * pidx;
        Vt[pi][kk] = Vb[(size_t)r * KK + kk];
    }
    for (int pi = tid; pi < 32; pi += 256) {
        int pidx = p0 + pi; if (pidx > 4096) pidx = 4096;
        int r = (pidx == 4096) ? 1 : 2 * pidx;
        int f = br13(r);
        const float invN = 1.f / 8192.f;
        float ph = -6.28318530717958647692f * (float)f * invN;
        float s1, c1, s2, c2;
        __sincosf(ph, &s1, &c1);
        __sincosf(2.f * ph, &s2, &c2);
        Vt[pi][24] = make_float2(invN, 0.f);
        Vt[pi][25] = make_float2(c1 * invN, s1 * invN);
        Vt[pi][26] = make_float2(c2 * invN, s2 * invN);
    }
    __syncthreads();

    const int lane = tid & 63, w = tid >> 6;
    const int rt = w & 1, chalf = w >> 1;
    const int lrow = lane & 15, lk = lane >> 4;
    const u16* axp = &Uxs[rt * 16 + lrow][lk * 8];
    const u16* ayp = &Uys[rt * 16 + lrow][lk * 8];

    float Sx0[4] = {0.f, 0.f, 0.f, 0.f}, Sy0[4] = {0.f, 0.f, 0.f, 0.f};
    float Sx1[4] = {0.f, 0.f, 0.f, 0.f}, Sy1[4] = {0.f, 0.f, 0.f, 0.f};

    for (int k = 0; k < KT; ++k) {
        const int cur = k & 1;
        bf16x8 ax0 = *(const bf16x8*)(axp);
        bf16x8 ax1 = *(const bf16x8*)(axp + 32);
        bf16x8 ay0 = *(const bf16x8*)(ayp);
        bf16x8 ay1 = *(const bf16x8*)(ayp + 32);
        const u16* bp0 = &mpT[cur][chalf * 32 + lrow][lk * 8];
        const u16* bp1 = &mpT[cur][chalf * 32 + 16 + lrow][lk * 8];
        bf16x8 b00 = *(const bf16x8*)(bp0);
        bf16x8 b01 = *(const bf16x8*)(bp0 + 32);
        bf16x8 b10 = *(const bf16x8*)(bp1);
        bf16x8 b11 = *(const bf16x8*)(bp1 + 32);
        float2 v0 = Vt[rt * 16 + lk * 4 + 0][k];
        float2 v1 = Vt[rt * 16 + lk * 4 + 1][k];
        float2 v2 = Vt[rt * 16 + lk * 4 + 2][k];
        float2 v3 = Vt[rt * 16 + lk * 4 + 3][k];
        if (k + 1 < KT) {
            int o = tid >> 2, seg = tid & 3;
            const uint4* src = (const uint4*)&mp2[((size_t)(k + 1) * 64 + o) * 32 + seg * 8];
            uint4 m0 = src[0], m1 = src[1];
            *(uint4*)&mpT[cur ^ 1][o][seg * 16] = m0;
            *(uint4*)&mpT[cur ^ 1][o][seg * 16 + 8] = m1;
        }
        f32x4 z = {0.f, 0.f, 0.f, 0.f};
        f32x4 Wx0 = __builtin_amdgcn_mfma_f32_16x16x32_bf16(ax0, b00, z, 0, 0, 0);
        Wx0 = __builtin_amdgcn_mfma_f32_16x16x32_bf16(ax1, b01, Wx0, 0, 0, 0);
        f32x4 Wy0 = __builtin_amdgcn_mfma_f32_16x16x32_bf16(ay0, b00, z, 0, 0, 0);
        Wy0 = __builtin_amdgcn_mfma_f32_16x16x32_bf16(ay1, b01, Wy0, 0, 0, 0);
        f32x4 Wx1 = __builtin_amdgcn_mfma_f32_16x16x32_bf16(ax0, b10, z, 0, 0, 0);
        Wx1 = __builtin_amdgcn_mfma_f32_16x16x32_bf16(ax1, b11, Wx1, 0, 0, 0);
        f32x4 Wy1 = __builtin_amdgcn_mfma_f32_16x16x32_bf16(ay0, b10, z, 0, 0, 0);
        Wy1 = __builtin_amdgcn_mfma_f32_16x16x32_bf16(ay1, b11, Wy1, 0, 0, 0);
        Sx0[0] += v0.x * Wx0[0] - v0.y * Wy0[0];  Sy0[0] += v0.x * Wy0[0] + v0.y * Wx0[0];
        Sx0[1] += v1.x * Wx0[1] - v1.y * Wy0[1];  Sy0[1] += v1.x * Wy0[1] + v1.y * Wx0[1];
        Sx0[2] += v2.x * Wx0[2] - v2.y * Wy0[2];  Sy0[2] += v2.x * Wy0[2] + v2.y * Wx0[2];
        Sx0[3] += v3.x * Wx0[3] - v3.y * Wy0[3];  Sy0[3] += v3.x * Wy0[3] + v3.y * Wx0[3];
        Sx1[0] += v0.x * Wx1[0] - v0.y * Wy1[0];  Sy1[0] += v0.x * Wy1[0] + v0.y * Wx1[0];
        Sx1[1] += v1.x * Wx1[1] - v1.y * Wy1[1];  Sy1[1] += v1.x * Wy1[1] + v1.y * Wx1[1];
        Sx1[2] += v2.x * Wx1[2] - v2.y * Wy1[2];  Sy1[2] += v2.x * Wy1[2] + v2.y * Wx1[2];
        Sx1[3] += v3.x * Wx1[3] - v3.y * Wy1[3];  Sy1[3] += v3.x * Wy1[3] + v3.y * Wx1[3];
        __syncthreads();
    }
    const int rbase = rt * 16 + lk * 4;
    const int o0 = chalf * 32 + lrow;
    const size_t pl0 = ((size_t)b * 64 + o0) * NP + p0 + rbase;
    const size_t pl1 = ((size_t)b * 64 + o0 + 16) * NP + p0 + rbase;
#pragma unroll
    for (int j = 0; j < 4; ++j) {
        Sb2[pl0 + j] = pk(Sx0[j]) | (pk(Sy0[j]) << 16);
        Sb2[pl1 + j] = pk(Sx1[j]) | (pk(Sy1[j]) << 16);
    }
}

// Two output channels per inverse FFT; plane-major S in, plane-major deltas out.
__global__ __launch_bounds__(512) void k_ifft2(const uint* __restrict__ Sb2,
                                               const float2* __restrict__ twc,
                                               float* __restrict__ deltas) {
    __shared__ float2 a[NN];
    const int b = blockIdx.x & 7, op = blockIdx.x >> 3;
    const int tid = threadIdx.x;
    const uint* s0 = &Sb2[((size_t)b * 64 + op * 2) * NP];
    const uint* s1 = &Sb2[((size_t)b * 64 + op * 2 + 1) * NP];
    for (int idx = tid; idx < 4097; idx += 512) {
        int r = (idx == 4096) ? 1 : 2 * idx;
        float2 A = unpk2(s0[idx]), B = unpk2(s1[idx]);
        a[r] = make_float2(A.x - B.y, A.y + B.x);
        int fn = br13(r);
        int q = br13((8192 - fn) & 8191);
        if (q != r) a[q] = make_float2(A.x + B.y, B.x - A.y);
    }
    __syncthreads();
    fft_dit<512>(a, twc);
    float* d0 = &deltas[((size_t)b * 64 + op * 2) * LL];
    float* d1 = &deltas[((size_t)b * 64 + op * 2 + 1) * LL];
    for (int l = tid; l < LL; l += 512) {
        d0[l] = a[l].x;
        d1[l] = a[l].y;
    }
}

// First squaring with companion matrix built on the fly from m_y.
__global__ __launch_bounds__(256) void k_matsq1(const float* __restrict__ m_y,
                                                float* __restrict__ C) {
    int idx = blockIdx.x * 256 + threadIdx.x;
    int r = idx >> 7, c = idx & 127;
    if (r >= 64) { C[idx] = m_y[(r - 64) * 128 + c]; return; }
    float acc = (c < 64) ? m_y[r * 128 + 64 + c] : 0.f;
#pragma unroll
    for (int i = 0; i < 64; ++i) acc += m_y[r * 128 + i] * m_y[i * 128 + c];
    C[idx] = acc;
}

__global__ __launch_bounds__(256) void k_matsq(const float* __restrict__ A,
                                               float* __restrict__ C) {
    int idx = blockIdx.x * 256 + threadIdx.x;
    int r = idx >> 7, c = idx & 127;
    float acc = 0.f;
#pragma unroll
    for (int i = 0; i < 128; ++i) acc += A[r * 128 + i] * A[i * 128 + c];
    C[idx] = acc;
}

// ---- hierarchical boundary-scan helpers ----
__device__ __forceinline__ void load_rowhalf(const float* __restrict__ P, int r, int h,
                                             float* __restrict__ p) {
#pragma unroll
    for (int i4 = 0; i4 < 16; ++i4) {
        float4 v = *(const float4*)&P[r * 128 + h * 64 + i4 * 4];
        p[4 * i4] = v.x; p[4 * i4 + 1] = v.y; p[4 * i4 + 2] = v.z; p[4 * i4 + 3] = v.w;
    }
}
__device__ __forceinline__ float dot64(const float* __restrict__ p, const float* s) {
    float a0 = 0.f, a1 = 0.f, a2 = 0.f, a3 = 0.f;
#pragma unroll
    for (int i4 = 0; i4 < 16; ++i4) {
        float4 w = *(const float4*)&s[i4 * 4];
        a0 += p[4 * i4] * w.x;  a1 += p[4 * i4 + 1] * w.y;
        a2 += p[4 * i4 + 2] * w.z;  a3 += p[4 * i4 + 3] * w.w;
    }
    return (a0 + a1) + (a2 + a3);
}

// Generic affine scan: per block, zero-init scan over `count` inputs with matrix P.
__global__ __launch_bounds__(256, 1) void k_scan(const float* __restrict__ P,
                                                 const float* __restrict__ in,
                                                 float* __restrict__ partial,
                                                 float* __restrict__ terminal,
                                                 const int count) {
    const int bx = blockIdx.x;
    const int tid = threadIdx.x;
    const int r = tid & 127, h = tid >> 7;
    __shared__ __align__(16) float scur[128];
    __shared__ float pacc[256];
    float p[64];
    load_rowhalf(P, r, h, p);
    if (tid < 128) scur[tid] = 0.f;
    __syncthreads();
    const size_t base = (size_t)bx * count * 128;
    for (int k = 0; k < count; ++k) {
        if (tid < 128) partial[base + (size_t)k * 128 + tid] = scur[tid];
        pacc[tid] = dot64(p, &scur[h * 64]);
        __syncthreads();
        if (tid < 128) scur[tid] = pacc[tid] + pacc[tid + 128] + in[base + (size_t)k * 128 + tid];
        __syncthreads();
    }
    if (tid < 128) terminal[(size_t)bx * 128 + tid] = scur[tid];
}

// Generic fixup: out[k] = P^k * Sinit + q[k].
__global__ __launch_bounds__(256, 1) void k_fixupg(const float* __restrict__ P,
                                                   const float* __restrict__ Sinit,
                                                   const float* __restrict__ q,
                                                   float* __restrict__ out,
                                                   const int count) {
    const int bx = blockIdx.x;
    const int tid = threadIdx.x;
    const int r = tid & 127, h = tid >> 7;
    __shared__ __align__(16) float scur[128];
    __shared__ float pacc[256];
    float p[64];
    load_rowhalf(P, r, h, p);
    if (tid < 128) scur[tid] = Sinit[(size_t)bx * 128 + tid];
    __syncthreads();
    const size_t base = (size_t)bx * count * 128;
    for (int k = 0; k < count; ++k) {
        if (tid < 128) out[base + (size_t)k * 128 + tid] = scur[tid] + q[base + (size_t)k * 128 + tid];
        if (k == count - 1) break;
        pacc[tid] = dot64(p, &scur[h * 64]);
        __syncthreads();
        if (tid < 128) scur[tid] = pacc[tid] + pacc[tid + 128];
        __syncthreads();
    }
}

// Per-chunk local recurrence (CH=16 steps), 2-wave split; plane-major deltas.
__global__ __launch_bounds__(128, 1) void k_chunk_local(const float* __restrict__ deltas,
                                                        const float* __restrict__ m_y,
                                                        float* __restrict__ term) {
    const int b = blockIdx.x >> 8, j = blockIdx.x & 255;
    const int tid = threadIdx.x;
    const int o = tid & 63, h = tid >> 6;
    __shared__ __align__(16) float y1s[64];
    __shared__ __align__(16) float y2s[64];
    __shared__ float pacc[128];
    float m1[32], m2[32];
#pragma unroll
    for (int i4 = 0; i4 < 8; ++i4) {
        float4 v1 = *(const float4*)&m_y[o * 128 + h * 32 + i4 * 4];
        float4 v2 = *(const float4*)&m_y[o * 128 + 64 + h * 32 + i4 * 4];
        m1[4 * i4] = v1.x; m1[4 * i4 + 1] = v1.y; m1[4 * i4 + 2] = v1.z; m1[4 * i4 + 3] = v1.w;
        m2[4 * i4] = v2.x; m2[4 * i4 + 1] = v2.y; m2[4 * i4 + 2] = v2.z; m2[4 * i4 + 3] = v2.w;
    }
    if (tid < 64) { y1s[tid] = 0.f; y2s[tid] = 0.f; }
    __syncthreads();
    const float* dl = &deltas[((size_t)b * 64 + o) * LL + j * CH];
    for (int t = 0; t < CH; ++t) {
        float a0 = 0.f, a1 = 0.f, a2 = 0.f, a3 = 0.f;
#pragma unroll
        for (int i4 = 0; i4 < 8; ++i4) {
            float4 w1 = *(const float4*)&y1s[h * 32 + i4 * 4];
            float4 w2 = *(const float4*)&y2s[h * 32 + i4 * 4];
            a0 += m1[4 * i4] * w1.x + m2[4 * i4] * w2.x;
            a1 += m1[4 * i4 + 1] * w1.y + m2[4 * i4 + 1] * w2.y;
            a2 += m1[4 * i4 + 2] * w1.z + m2[4 * i4 + 2] * w2.z;
            a3 += m1[4 * i4 + 3] * w1.w + m2[4 * i4 + 3] * w2.w;
        }
        pacc[tid] = (a0 + a1) + (a2 + a3);
        __syncthreads();
        if (h == 0) {
            float outv = pacc[o] + pacc[o + 64] + dl[t];
            y2s[o] = y1s[o];
            y1s[o] = outv;
        }
        __syncthreads();
    }
    if (tid < 64) {
        term[((size_t)b * NCH + j) * 128 + o] = y1s[o];
        term[((size_t)b * NCH + j) * 128 + 64 + o] = y2s[o];
    }
}

// Per-chunk final recurrence with true initial states; writes row-major out.
__global__ __launch_bounds__(128, 1) void k_chunk_final(const float* __restrict__ deltas,
                                                        const float* __restrict__ m_y,
                                                        const float* __restrict__ sstate,
                                                        float* __restrict__ out) {
    const int b = blockIdx.x >> 8, j = blockIdx.x & 255;
    const int tid = threadIdx.x;
    const int o = tid & 63, h = tid >> 6;
    __shared__ __align__(16) float y1s[64];
    __shared__ __align__(16) float y2s[64];
    __shared__ float pacc[128];
    float m1[32], m2[32];
#pragma unroll
    for (int i4 = 0; i4 < 8; ++i4) {
        float4 v1 = *(const float4*)&m_y[o * 128 + h * 32 + i4 * 4];
        float4 v2 = *(const float4*)&m_y[o * 128 + 64 + h * 32 + i4 * 4];
        m1[4 * i4] = v1.x; m1[4 * i4 + 1] = v1.y; m1[4 * i4 + 2] = v1.z; m1[4 * i4 + 3] = v1.w;
        m2[4 * i4] = v2.x; m2[4 * i4 + 1] = v2.y; m2[4 * i4 + 2] = v2.z; m2[4 * i4 + 3] = v2.w;
    }
    if (tid < 64) {
        y1s[tid] = sstate[((size_t)b * NCH + j) * 128 + tid];
        y2s[tid] = sstate[((size_t)b * NCH + j) * 128 + 64 + tid];
    }
    __syncthreads();
    const float* dl = &deltas[((size_t)b * 64 + o) * LL + j * CH];
    const size_t obase = (((size_t)b * LL) + j * CH) * DD + o;
    for (int t = 0; t < CH; ++t) {
        float a0 = 0.f, a1 = 0.f, a2 = 0.f, a3 = 0.f;
#pragma unroll
        for (int i4 = 0; i4 < 8; ++i4) {
            float4 w1 = *(const float4*)&y1s[h * 32 + i4 * 4];
            float4 w2 = *(const float4*)&y2s[h * 32 + i4 * 4];
            a0 += m1[4 * i4] * w1.x + m2[4 * i4] * w2.x;
            a1 += m1[4 * i4 + 1] * w1.y + m2[4 * i4 + 1] * w2.y;
            a2 += m1[4 * i4 + 2] * w1.z + m2[4 * i4 + 2] * w2.z;
            a3 += m1[4 * i4 + 3] * w1.w + m2[4 * i4 + 3] * w2.w;
        }
        pacc[tid] = (a0 + a1) + (a2 + a3);
        __syncthreads();
        if (h == 0) {
            float outv = pacc[o] + pacc[o + 64] + dl[t];
            out[obase + (size_t)t * DD] = outv;
            y2s[o] = y1s[o];
            y1s[o] = outv;
        }
        __syncthreads();
    }
}

extern "C" void kernel_launch(void* const* d_in, const int* in_sizes, int n_in,
                              void* d_out, int out_size, void* d_ws, size_t ws_size,
                              hipStream_t stream) {
    const float* x        = (const float*)d_in[0];
    const float* m_y      = (const float*)d_in[1];
    const float* m_u      = (const float*)d_in[2];
    const float* m_phi    = (const float*)d_in[3];
    const float* eig_vals = (const float*)d_in[4];
    const float* eig_vecs = (const float*)d_in[5];
    float* out = (float*)d_out;

    char* ws = (char*)d_ws;
    size_t off = 0;
    auto alloc = [&](size_t bytes) -> void* {
        void* p = ws + off;
        off += (bytes + 255) & ~(size_t)255;
        return p;
    };
    float2* Vb   = (float2*)alloc((size_t)NN * KK * sizeof(float2));          // 1.6 MB
    uint*   Uxp  = (uint*)alloc((size_t)BB * 32 * NP * sizeof(uint));         // 4.2 MB
    uint*   Uyp  = (uint*)alloc((size_t)BB * 32 * NP * sizeof(uint));         // 4.2 MB
    uint*   Sb2  = (uint*)alloc((size_t)BB * 64 * NP * sizeof(uint));         // 8.5 MB
    float*  deltas = (float*)alloc((size_t)BB * 64 * LL * sizeof(float));     // 8.4 MB (plane-major)
    uint*   mp2  = (uint*)alloc((size_t)KT * 64 * 32 * sizeof(uint));         // 0.22 MB
    float2* twcg = (float2*)alloc((size_t)8192 * sizeof(float2));             // 64 KB
    float*  mats = (float*)alloc((size_t)4 * 128 * 128 * sizeof(float));
    float*  term = (float*)alloc((size_t)BB * NCH * 128 * sizeof(float));
    float*  sst  = (float*)alloc((size_t)BB * NCH * 128 * sizeof(float));
    float*  qbuf = (float*)alloc((size_t)BB * NCH * 128 * sizeof(float));
    float*  Qg   = (float*)alloc((size_t)BB * 16 * 128 * sizeof(float));
    float*  Sgt  = (float*)alloc((size_t)BB * 16 * 128 * sizeof(float));
    float*  dmy  = (float*)alloc((size_t)8 * 128 * sizeof(float));

    k_packtw<<<dim3(248), dim3(256), 0, stream>>>(m_phi, m_u, mp2, twcg);
    k_fft_all<<<dim3(280), dim3(512), 0, stream>>>(x, eig_vals, eig_vecs, twcg, Uxp, Uyp, Vb);

    float* T1   = mats;
    float* T2   = mats + 16384;
    float* P16  = mats + 32768;
    float* P256 = mats + 49152;
    k_matsq1<<<dim3(64), dim3(256), 0, stream>>>(m_y, T1);   // M^2
    k_matsq<<<dim3(64), dim3(256), 0, stream>>>(T1, T2);     // M^4
    k_matsq<<<dim3(64), dim3(256), 0, stream>>>(T2, T1);     // M^8
    k_matsq<<<dim3(64), dim3(256), 0, stream>>>(T1, P16);    // M^16
    k_matsq<<<dim3(64), dim3(256), 0, stream>>>(P16, T1);    // M^32
    k_matsq<<<dim3(64), dim3(256), 0, stream>>>(T1, T2);     // M^64
    k_matsq<<<dim3(64), dim3(256), 0, stream>>>(T2, T1);     // M^128
    k_matsq<<<dim3(64), dim3(256), 0, stream>>>(T1, P256);   // M^256

    k_modulate5<<<dim3(129, 8), dim3(256), 0, stream>>>(Vb, Uxp, Uyp, mp2, Sb2);
    k_ifft2<<<dim3(256), dim3(512), 0, stream>>>(Sb2, twcg, deltas);

    k_chunk_local<<<dim3(2048), dim3(128), 0, stream>>>(deltas, m_y, term);
    k_scan<<<dim3(128), dim3(256), 0, stream>>>(P16, term, qbuf, Qg, 16);   // per (b,g<16)
    k_scan<<<dim3(8), dim3(256), 0, stream>>>(P256, Qg, Sgt, dmy, 16);      // per b -> group inits
    k_fixupg<<<dim3(128), dim3(256), 0, stream>>>(P16, Sgt, qbuf, sst, 16); // chunk inits
    k_chunk_final<<<dim3(2048), dim3(128), 0, stream>>>(deltas, m_y, sst, out);
}